// Round 2
// baseline (10666.260 us; speedup 1.0000x reference)
//
#include <hip/hip_runtime.h>
#include <hip/hip_bf16.h>

typedef __hip_bfloat16 bf16;

__device__ __forceinline__ float ld_f(const float* p, size_t i) { return p[i]; }
__device__ __forceinline__ float ld_f(const bf16* p, size_t i) { return __bfloat162float(p[i]); }
__device__ __forceinline__ void st_f(float* p, size_t i, float v) { p[i] = v; }
__device__ __forceinline__ void st_f(bf16* p, size_t i, float v) { p[i] = __float2bfloat16(v); }
__device__ __forceinline__ float bf16bits_to_f(unsigned short u) {
    return __uint_as_float(((unsigned int)u) << 16);
}
__device__ __forceinline__ float sigmoidf_(float x) { return 1.0f / (1.0f + expf(-x)); }

// ---------------------------------------------------------------------------
// zero fill (replaces hipMemsetAsync to stay graph-capture-trivial)
// ---------------------------------------------------------------------------
__global__ __launch_bounds__(256) void zero_kernel(float* __restrict__ p, int n) {
    int i = blockIdx.x * 256 + threadIdx.x;
    if (i < n) p[i] = 0.0f;
}

// ---------------------------------------------------------------------------
// conv1 stats: per-channel sum/sumsq of PRE-BN conv1 output. No y1 store.
// grid (64 n, 4 chunk-groups), block 256. Each thread owns 2 channels.
// ---------------------------------------------------------------------------
__global__ __launch_bounds__(256) void conv1_stats(const float* __restrict__ x,
                                                   const float* __restrict__ w1,
                                                   float* __restrict__ sums) {
    const int n = blockIdx.x;
    const int tid = threadIdx.x;
    __shared__ __align__(16) float ws[5120];
    __shared__ __align__(16) float xs[5 * 256 + 10];
    for (int e = tid; e < 5120; e += 256) ws[e] = w1[e];
    const int co0 = tid, co1 = tid + 256;
    float a1_0 = 0.0f, a2_0 = 0.0f, a1_1 = 0.0f, a2_1 = 0.0f;
    for (int i = 0; i < 4; ++i) {
        const int c = blockIdx.y * 4 + i;           // chunk of 256 output positions
        const int base = c * 1280 - 3;
        __syncthreads();
        for (int e = tid; e < 1290; e += 256) {
            int g = base + e;
            xs[e] = (g >= 0 && g < 20480) ? x[(size_t)n * 20480 + g] : 0.0f;
        }
        __syncthreads();
        for (int l = 0; l < 256; ++l) {
            float y0 = 0.0f, y1v = 0.0f;
#pragma unroll
            for (int t = 0; t < 10; ++t) {
                float xv = xs[5 * l + t];
                y0 += ws[co0 * 10 + t] * xv;
                y1v += ws[co1 * 10 + t] * xv;
            }
            a1_0 += y0; a2_0 += y0 * y0;
            a1_1 += y1v; a2_1 += y1v * y1v;
        }
    }
    atomicAdd(&sums[co0], a1_0); atomicAdd(&sums[512 + co0], a2_0);
    atomicAdd(&sums[co1], a1_1); atomicAdd(&sums[512 + co1], a2_1);
}

__global__ __launch_bounds__(256) void bn1_finalize(const float* __restrict__ sums,
                                                    const float* __restrict__ gamma,
                                                    const float* __restrict__ beta,
                                                    float* __restrict__ ss) {
    int c = blockIdx.x * 256 + threadIdx.x;
    if (c >= 512) return;
    const float invM = 1.0f / (64.0f * 4096.0f);
    float mean = sums[c] * invM;
    float var = sums[512 + c] * invM - mean * mean;
    float sc = rsqrtf(var + 1e-5f) * gamma[c];
    ss[c] = sc;
    ss[512 + c] = beta[c] - mean * sc;
}

// ---------------------------------------------------------------------------
// conv1 apply (per 8-batch chunk): y1c[nloc,co,l] = relu(sc*conv1 + sh), bf16
// ---------------------------------------------------------------------------
__global__ __launch_bounds__(256) void conv1_apply(const float* __restrict__ x,
                                                   const float* __restrict__ w1,
                                                   const float* __restrict__ ss,
                                                   bf16* __restrict__ y1c, int nbase) {
    __shared__ __align__(16) float xs[5 * 64 + 10 + 1];
    __shared__ __align__(16) float ws[5120];
    const int lt = blockIdx.x, nloc = blockIdx.y;
    const int n = nbase + nloc;
    const int l0 = lt * 64;
    const int base = l0 * 5 - 3;
    for (int e = threadIdx.x; e < 5 * 64 + 10; e += 256) {
        int g = base + e;
        xs[e] = (g >= 0 && g < 20480) ? x[(size_t)n * 20480 + g] : 0.0f;
    }
    for (int e = threadIdx.x; e < 5120; e += 256) ws[e] = w1[e];
    __syncthreads();
    for (int idx = threadIdx.x; idx < 512 * 64; idx += 256) {
        int co = idx >> 6, l = idx & 63;
        float acc = 0.0f;
#pragma unroll
        for (int t = 0; t < 10; ++t) acc += ws[co * 10 + t] * xs[5 * l + t];
        float v = fmaxf(acc * ss[co] + ss[512 + co], 0.0f);
        y1c[((size_t)nloc * 512 + co) * 4096 + l0 + l] = __float2bfloat16(v);
    }
}

// ---------------------------------------------------------------------------
// BN batch-stats (sum, sumsq per channel) + apply (affine + relu), in place
// ---------------------------------------------------------------------------
template <typename T>
__global__ __launch_bounds__(256) void bn_stats(const T* __restrict__ y, float* __restrict__ sums, int L) {
    const int c = blockIdx.x;
    float s1 = 0.0f, s2 = 0.0f;
    for (int n = 0; n < 64; ++n) {
        const T* p = y + ((size_t)n * 512 + c) * L;
        for (int l = blockIdx.y * 256 + threadIdx.x; l < L; l += gridDim.y * 256) {
            float v = ld_f(p, l);
            s1 += v; s2 += v * v;
        }
    }
    __shared__ float r1[256], r2[256];
    r1[threadIdx.x] = s1; r2[threadIdx.x] = s2;
    __syncthreads();
    for (int o = 128; o > 0; o >>= 1) {
        if (threadIdx.x < o) { r1[threadIdx.x] += r1[threadIdx.x + o]; r2[threadIdx.x] += r2[threadIdx.x + o]; }
        __syncthreads();
    }
    if (threadIdx.x == 0) {
        atomicAdd(&sums[c], r1[0]);
        atomicAdd(&sums[512 + c], r2[0]);
    }
}

template <typename T>
__global__ __launch_bounds__(256) void bn_apply(T* __restrict__ y, const float* __restrict__ sums,
                                                const float* __restrict__ gamma, const float* __restrict__ beta,
                                                int layer, int L) {
    const int c = blockIdx.x;
    const float invM = 1.0f / (64.0f * (float)L);
    float mean = sums[c] * invM;
    float var = sums[512 + c] * invM - mean * mean;
    float sc = rsqrtf(var + 1e-5f) * gamma[layer * 512 + c];
    float sh = beta[layer * 512 + c] - mean * sc;
    for (int n = 0; n < 64; ++n) {
        T* p = y + ((size_t)n * 512 + c) * L;
        for (int l = blockIdx.y * 256 + threadIdx.x; l < L; l += gridDim.y * 256) {
            float v = ld_f(p, l);
            st_f(p, l, fmaxf(v * sc + sh, 0.0f));
        }
    }
}

// ---------------------------------------------------------------------------
// Generic strided conv as tiled GEMM. out[n,co,l] = sum_{ci,t} w[co,ci,t]*in[n,ci,ST*l-pad+t]
// Tile: 64 co x 64 l, K-chunk = CC channels * KW taps. 256 threads, 4x4 acc.
// ---------------------------------------------------------------------------
template <int KW, int ST, int CC, typename TIN, typename TOUT>
__global__ __launch_bounds__(256) void conv_gemm(const TIN* __restrict__ in, const float* __restrict__ w,
                                                 TOUT* __restrict__ out, int Lin, int Lout, int pad) {
    constexpr int BK = CC * KW;
    constexpr int SPAN = ST * 64 + KW;
    const int l0 = blockIdx.x * 64, co0 = blockIdx.y * 64;
    const int n = blockIdx.z;
    const int tid = threadIdx.x;
    const int tx = tid & 15, ty = tid >> 4;

    __shared__ __align__(16) float Ast[BK][68];       // [k][co] transposed weights
    __shared__ __align__(16) float Bs[BK][64];        // [k][l] patches
    __shared__ __align__(16) float rows[CC][SPAN + 1];

    float acc[4][4] = {};
    const int base = ST * l0 - pad;
    const float* wbase = w + (size_t)co0 * 512 * KW;
    const TIN* inbase = in + (size_t)n * 512 * Lin;

    for (int ci0 = 0; ci0 < 512; ci0 += CC) {
        __syncthreads();
        for (int e = tid; e < 64 * BK; e += 256) {
            int row = e / BK, j = e - row * BK;
            Ast[j][row] = wbase[(size_t)row * 512 * KW + (size_t)ci0 * KW + j];
        }
        for (int e = tid; e < CC * SPAN; e += 256) {
            int cc = e / SPAN, j = e - cc * SPAN;
            int g = base + j;
            float v = 0.0f;
            if (g >= 0 && g < Lin) v = ld_f(inbase, (size_t)(ci0 + cc) * Lin + g);
            rows[cc][j] = v;
        }
        __syncthreads();
        for (int e = tid; e < BK * 64; e += 256) {
            int k = e >> 6, l = e & 63;
            int cc = k / KW, t = k - cc * KW;
            Bs[k][l] = rows[cc][ST * l + t];
        }
        __syncthreads();
#pragma unroll
        for (int k = 0; k < BK; ++k) {
            float4 a = *(const float4*)&Ast[k][ty * 4];
            float4 bv = *(const float4*)&Bs[k][tx * 4];
            acc[0][0] += a.x * bv.x; acc[0][1] += a.x * bv.y; acc[0][2] += a.x * bv.z; acc[0][3] += a.x * bv.w;
            acc[1][0] += a.y * bv.x; acc[1][1] += a.y * bv.y; acc[1][2] += a.y * bv.z; acc[1][3] += a.y * bv.w;
            acc[2][0] += a.z * bv.x; acc[2][1] += a.z * bv.y; acc[2][2] += a.z * bv.z; acc[2][3] += a.z * bv.w;
            acc[3][0] += a.w * bv.x; acc[3][1] += a.w * bv.y; acc[3][2] += a.w * bv.z; acc[3][3] += a.w * bv.w;
        }
    }
#pragma unroll
    for (int i = 0; i < 4; ++i) {
        int co = co0 + ty * 4 + i;
#pragma unroll
        for (int j = 0; j < 4; ++j) {
            int l = l0 + tx * 4 + j;
            if (l < Lout) st_f(out, ((size_t)n * 512 + co) * Lout + l, acc[i][j]);
        }
    }
}

// ---------------------------------------------------------------------------
// x_proj[b,t,g] = sum_d y5[b,d,t]*wih[g,d] + bih[g]   (t <= ts)
// ---------------------------------------------------------------------------
__global__ __launch_bounds__(256) void xproj_kernel(const bf16* __restrict__ y5, const float* __restrict__ wih,
                                                    const float* __restrict__ bih, float* __restrict__ xp,
                                                    const int* __restrict__ tsamp) {
    const int g0 = blockIdx.x * 64, t0 = blockIdx.y * 64;
    const int b = blockIdx.z;
    const int tid = threadIdx.x;
    const int tx = tid & 15, ty = tid >> 4;
    const int ts = tsamp[0];

    __shared__ __align__(16) float As[32][68];    // [d][t]
    __shared__ __align__(16) float Bst[32][68];   // [d][g]
    float acc[4][4] = {};
    const bf16* ybase = y5 + (size_t)b * 512 * 409;
    for (int d0 = 0; d0 < 512; d0 += 32) {
        __syncthreads();
        for (int e = tid; e < 32 * 64; e += 256) {
            int dj = e >> 6, tl = e & 63;
            As[dj][tl] = ld_f(ybase, (size_t)(d0 + dj) * 409 + t0 + tl);  // t0+tl <= 255 < 409
        }
        for (int e = tid; e < 64 * 32; e += 256) {
            int gr = e >> 5, dj = e & 31;
            Bst[dj][gr] = wih[(size_t)(g0 + gr) * 512 + d0 + dj];
        }
        __syncthreads();
#pragma unroll
        for (int k = 0; k < 32; ++k) {
            float4 a = *(const float4*)&As[k][ty * 4];
            float4 bv = *(const float4*)&Bst[k][tx * 4];
            acc[0][0] += a.x * bv.x; acc[0][1] += a.x * bv.y; acc[0][2] += a.x * bv.z; acc[0][3] += a.x * bv.w;
            acc[1][0] += a.y * bv.x; acc[1][1] += a.y * bv.y; acc[1][2] += a.y * bv.z; acc[1][3] += a.y * bv.w;
            acc[2][0] += a.z * bv.x; acc[2][1] += a.z * bv.y; acc[2][2] += a.z * bv.z; acc[2][3] += a.z * bv.w;
            acc[3][0] += a.w * bv.x; acc[3][1] += a.w * bv.y; acc[3][2] += a.w * bv.z; acc[3][3] += a.w * bv.w;
        }
    }
#pragma unroll
    for (int i = 0; i < 4; ++i) {
        int t = t0 + ty * 4 + i;
        if (t <= ts) {
            float4 o;
            o.x = acc[i][0] + bih[g0 + tx * 4 + 0];
            o.y = acc[i][1] + bih[g0 + tx * 4 + 1];
            o.z = acc[i][2] + bih[g0 + tx * 4 + 2];
            o.w = acc[i][3] + bih[g0 + tx * 4 + 3];
            *(float4*)&xp[((size_t)b * 256 + t) * 768 + g0 + tx * 4] = o;
        }
    }
}

// ---------------------------------------------------------------------------
// pack whh (768,256) fp32 -> wpk[(d/4)*768 + col] = ushort4 of bf16 {d..d+3}
// ---------------------------------------------------------------------------
__global__ __launch_bounds__(256) void pack_whh(const float* __restrict__ whh, ushort4* __restrict__ wpk) {
    int idx = blockIdx.x * 256 + threadIdx.x;
    if (idx >= 64 * 768) return;
    int d4 = idx / 768, g = idx - d4 * 768;
    float4 v = *(const float4*)(whh + (size_t)g * 256 + d4 * 4);
    bf16 a = __float2bfloat16(v.x), b = __float2bfloat16(v.y), c = __float2bfloat16(v.z), d = __float2bfloat16(v.w);
    ushort4 o;
    o.x = *reinterpret_cast<unsigned short*>(&a);
    o.y = *reinterpret_cast<unsigned short*>(&b);
    o.z = *reinterpret_cast<unsigned short*>(&c);
    o.w = *reinterpret_cast<unsigned short*>(&d);
    wpk[idx] = o;
}

// ---------------------------------------------------------------------------
// GRU: one block per batch element, h (256) in LDS, ts+1 sequential steps.
// ---------------------------------------------------------------------------
__global__ __launch_bounds__(256) void gru_kernel(const float* __restrict__ xproj, const ushort4* __restrict__ wpk,
                                                  const float* __restrict__ hidden, const float* __restrict__ bhh,
                                                  float* __restrict__ hlast, const int* __restrict__ tsamp) {
    const int b = blockIdx.x;
    const int g = threadIdx.x;
    __shared__ __align__(16) float h[256];
    h[g] = hidden[(size_t)b * 256 + g];
    const float bhr = bhh[g], bhz = bhh[256 + g], bhn = bhh[512 + g];
    const int ts = tsamp[0];
    const float* xp = xproj + (size_t)b * 256 * 768;
    __syncthreads();
    for (int step = 0; step <= ts; ++step) {
        float ar = 0.0f, az = 0.0f, an = 0.0f;
#pragma unroll 4
        for (int d4 = 0; d4 < 64; ++d4) {
            float4 hv = *(const float4*)&h[d4 * 4];
            ushort4 wr = wpk[d4 * 768 + g];
            ushort4 wz = wpk[d4 * 768 + 256 + g];
            ushort4 wn = wpk[d4 * 768 + 512 + g];
            ar += bf16bits_to_f(wr.x) * hv.x + bf16bits_to_f(wr.y) * hv.y +
                  bf16bits_to_f(wr.z) * hv.z + bf16bits_to_f(wr.w) * hv.w;
            az += bf16bits_to_f(wz.x) * hv.x + bf16bits_to_f(wz.y) * hv.y +
                  bf16bits_to_f(wz.z) * hv.z + bf16bits_to_f(wz.w) * hv.w;
            an += bf16bits_to_f(wn.x) * hv.x + bf16bits_to_f(wn.y) * hv.y +
                  bf16bits_to_f(wn.z) * hv.z + bf16bits_to_f(wn.w) * hv.w;
        }
        float xr = xp[(size_t)step * 768 + g];
        float xz = xp[(size_t)step * 768 + 256 + g];
        float xn = xp[(size_t)step * 768 + 512 + g];
        float r = sigmoidf_(xr + ar + bhr);
        float z = sigmoidf_(xz + az + bhz);
        float nn = tanhf(xn + r * (an + bhn));
        float hnew = (1.0f - z) * nn + z * h[g];
        __syncthreads();
        h[g] = hnew;
        __syncthreads();
    }
    hlast[(size_t)b * 256 + g] = h[g];
}

// ---------------------------------------------------------------------------
// pred[t,c,k] = sum_d hlast[c,d]*wkw[t,k,d] + wkb[t,k]
// ---------------------------------------------------------------------------
__global__ __launch_bounds__(256) void pred_kernel(const float* __restrict__ hlast, const float* __restrict__ wkw,
                                                   const float* __restrict__ wkb, float* __restrict__ pred) {
    const int c = blockIdx.x, t = blockIdx.y;
    __shared__ __align__(16) float hs[256];
    hs[threadIdx.x] = hlast[(size_t)c * 256 + threadIdx.x];
    __syncthreads();
    for (int k = threadIdx.x; k < 512; k += 256) {
        const float* wr = wkw + ((size_t)t * 512 + k) * 256;
        float acc = 0.0f;
        for (int d = 0; d < 256; d += 4) {
            float4 w4 = *(const float4*)&wr[d];
            acc += w4.x * hs[d] + w4.y * hs[d + 1] + w4.z * hs[d + 2] + w4.w * hs[d + 3];
        }
        pred[((size_t)t * 64 + c) * 512 + k] = acc + wkb[(size_t)t * 512 + k];
    }
}

// ---------------------------------------------------------------------------
// total[t,b,c] = sum_k y5[b,k,ts+1+t] * pred[t,c,k]
// ---------------------------------------------------------------------------
__global__ __launch_bounds__(64) void total_kernel(const bf16* __restrict__ y5, const float* __restrict__ pred,
                                                   float* __restrict__ total, const int* __restrict__ tsamp) {
    const int b = blockIdx.x, t = blockIdx.y;
    const int col = tsamp[0] + 1 + t;
    __shared__ __align__(16) float es[512];
    for (int k = threadIdx.x; k < 512; k += 64) es[k] = ld_f(y5, ((size_t)b * 512 + k) * 409 + col);
    __syncthreads();
    const int c = threadIdx.x;
    const float* pr = pred + ((size_t)t * 64 + c) * 512;
    float acc = 0.0f;
    for (int k = 0; k < 512; k += 4) {
        float4 p4 = *(const float4*)&pr[k];
        acc += p4.x * es[k] + p4.y * es[k + 1] + p4.z * es[k + 2] + p4.w * es[k + 3];
    }
    total[((size_t)t * 64 + b) * 64 + c] = acc;
}

// ---------------------------------------------------------------------------
// final: log_softmax diag -> nce; softmax(total[11]) argmax -> accuracy; copy h
// ---------------------------------------------------------------------------
__global__ __launch_bounds__(256) void final_kernel(const float* __restrict__ total, const float* __restrict__ hlast,
                                                    float* __restrict__ out) {
    __shared__ float rowM[768], rowS[768];
    __shared__ float red[256];
    __shared__ int cnt[64];
    const int tid = threadIdx.x;
    float local = 0.0f;
    for (int row = tid; row < 768; row += 256) {
        const float* r = total + (size_t)row * 64;
        float m = r[0];
        for (int c = 1; c < 64; ++c) m = fmaxf(m, r[c]);
        float s = 0.0f;
        for (int c = 0; c < 64; ++c) s += expf(r[c] - m);
        rowM[row] = m; rowS[row] = s;
        int bcol = row & 63;
        local += r[bcol] - m - logf(s);
    }
    red[tid] = local;
    __syncthreads();
    for (int o = 128; o > 0; o >>= 1) {
        if (tid < o) red[tid] += red[tid + o];
        __syncthreads();
    }
    if (tid == 0) out[1] = red[0] / (-768.0f);
    if (tid < 64) {
        const int c = tid;
        float best = -1e30f; int bi = -1;
        for (int b = 0; b < 64; ++b) {
            int row = 11 * 64 + b;
            float v = expf(total[(size_t)row * 64 + c] - rowM[row]) / rowS[row];
            if (v > best) { best = v; bi = b; }
        }
        cnt[c] = (bi == c) ? 1 : 0;
    }
    __syncthreads();
    if (tid == 0) {
        int s = 0;
        for (int c = 0; c < 64; ++c) s += cnt[c];
        out[0] = (float)s / 64.0f;
    }
    for (int i = tid; i < 16384; i += 256) out[2 + i] = hlast[i];
}

// ---------------------------------------------------------------------------
extern "C" void kernel_launch(void* const* d_in, const int* in_sizes, int n_in,
                              void* d_out, int out_size, void* d_ws, size_t ws_size,
                              hipStream_t stream) {
    const float *x = nullptr, *hidden = nullptr, *gamma = nullptr, *beta = nullptr;
    const float *wih = nullptr, *whh = nullptr, *bih = nullptr, *bhh = nullptr;
    const float *wkw = nullptr, *wkb = nullptr;
    const float *w1 = nullptr, *w2 = nullptr, *w3 = nullptr, *w4 = nullptr, *w5 = nullptr;
    const int* tsamp = nullptr;
    for (int i = 0; i < n_in; ++i) {
        const float* p = (const float*)d_in[i];
        switch (in_sizes[i]) {
            case 1310720: x = p; break;
            case 16384:   hidden = p; break;
            case 2560:    if (!gamma) gamma = p; else beta = p; break;
            case 393216:  wih = p; break;
            case 196608:  whh = p; break;
            case 768:     if (!bih) bih = p; else bhh = p; break;
            case 1572864: wkw = p; break;
            case 6144:    wkb = p; break;
            case 1:       tsamp = (const int*)d_in[i]; break;
            case 5120:    w1 = p; break;
            case 2097152: w2 = p; break;
            case 1048576: w3 = p; break;
            case 786432:  if (!w4) w4 = p; else w5 = p; break;
            default: break;
        }
    }

    // Workspace layout (peak ~92.3 MB):
    //   phase A (encoder L1/L2): y2 [0,53.7M), y1c [56M,89.6M), tail [90M+)
    //   phase B: y3 [56M,82.8M), y4 [0,26.8M), y5(bf16) [56M,82.8M), xp [0,50.3M)
    char* ws = (char*)d_ws;
    bf16*  y2    = (bf16*)(ws + 0);                 // 53,673,984 B
    bf16*  y1c   = (bf16*)(ws + 56000000ull);       // 33,554,432 B (8-batch chunk)
    bf16*  y3    = (bf16*)(ws + 56000000ull);       // 26,804,224 B (after y1c dead)
    bf16*  y4    = (bf16*)(ws + 0);                 // 26,804,224 B (after y2 dead)
    bf16*  y5    = (bf16*)(ws + 56000000ull);       // 26,804,224 B (after y3 dead)
    float* xp    = (float*)(ws + 0);                // 50,331,648 B (after y4 dead)
    float* sums  = (float*)(ws + 90000000ull);      //     20,480 B (5 layers x 1024 f)
    float* ss1   = (float*)(ws + 90020480ull);      //      4,096 B
    ushort4* wpk = (ushort4*)(ws + 90024576ull);    //    393,216 B
    float* hlast = (float*)(ws + 90417792ull);      //     65,536 B
    float* pred  = (float*)(ws + 90483328ull);      //  1,572,864 B
    float* totl  = (float*)(ws + 92056192ull);      //    196,608 B  -> end 92,252,800

    // --- layer 1 stats (no y1 materialization) ---
    zero_kernel<<<20, 256, 0, stream>>>(sums, 5120);
    conv1_stats<<<dim3(64, 4), 256, 0, stream>>>(x, w1, sums);
    bn1_finalize<<<2, 256, 0, stream>>>(sums, gamma, beta, ss1);

    // --- layer 1 apply + layer 2 conv, in 8-batch chunks ---
    for (int nb = 0; nb < 64; nb += 8) {
        conv1_apply<<<dim3(64, 8), 256, 0, stream>>>(x, w1, ss1, y1c, nb);
        conv_gemm<8, 5, 4, bf16, bf16><<<dim3(13, 8, 8), 256, 0, stream>>>(
            y1c, w2, y2 + (size_t)nb * 512 * 819, 4096, 819, 2);
    }
    bn_stats<bf16><<<dim3(512, 3), 256, 0, stream>>>(y2, sums + 1024, 819);
    bn_apply<bf16><<<dim3(512, 3), 256, 0, stream>>>(y2, sums + 1024, gamma, beta, 1, 819);

    conv_gemm<4, 2, 8, bf16, bf16><<<dim3(7, 8, 64), 256, 0, stream>>>(y2, w3, y3, 819, 409, 1);
    bn_stats<bf16><<<dim3(512, 2), 256, 0, stream>>>(y3, sums + 2048, 409);
    bn_apply<bf16><<<dim3(512, 2), 256, 0, stream>>>(y3, sums + 2048, gamma, beta, 2, 409);

    conv_gemm<3, 1, 8, bf16, bf16><<<dim3(7, 8, 64), 256, 0, stream>>>(y3, w4, y4, 409, 409, 1);
    bn_stats<bf16><<<dim3(512, 2), 256, 0, stream>>>(y4, sums + 3072, 409);
    bn_apply<bf16><<<dim3(512, 2), 256, 0, stream>>>(y4, sums + 3072, gamma, beta, 3, 409);

    conv_gemm<3, 1, 8, bf16, bf16><<<dim3(7, 8, 64), 256, 0, stream>>>(y4, w5, y5, 409, 409, 1);
    bn_stats<bf16><<<dim3(512, 2), 256, 0, stream>>>(y5, sums + 4096, 409);
    bn_apply<bf16><<<dim3(512, 2), 256, 0, stream>>>(y5, sums + 4096, gamma, beta, 4, 409);

    // --- GRU ---
    pack_whh<<<192, 256, 0, stream>>>(whh, wpk);
    xproj_kernel<<<dim3(12, 4, 64), 256, 0, stream>>>(y5, wih, bih, xp, tsamp);
    gru_kernel<<<64, 256, 0, stream>>>(xp, wpk, hidden, bhh, hlast, tsamp);

    // --- contrastive head ---
    pred_kernel<<<dim3(64, 12), 256, 0, stream>>>(hlast, wkw, wkb, pred);
    total_kernel<<<dim3(64, 12), 64, 0, stream>>>(y5, pred, totl, tsamp);
    final_kernel<<<1, 256, 0, stream>>>(totl, hlast, (float*)d_out);
}

// Round 3
// 7123.402 us; speedup vs baseline: 1.4974x; 1.4974x over previous
//
#include <hip/hip_runtime.h>
#include <hip/hip_bf16.h>

typedef __hip_bfloat16 bf16;
typedef short short8v __attribute__((ext_vector_type(8)));
typedef float float4v __attribute__((ext_vector_type(4)));

__device__ __forceinline__ float ld_f(const float* p, size_t i) { return p[i]; }
__device__ __forceinline__ float ld_f(const bf16* p, size_t i) { return __bfloat162float(p[i]); }
__device__ __forceinline__ void st_f(float* p, size_t i, float v) { p[i] = v; }
__device__ __forceinline__ void st_f(bf16* p, size_t i, float v) { p[i] = __float2bfloat16(v); }
__device__ __forceinline__ float bf16bits_to_f(unsigned short u) {
    return __uint_as_float(((unsigned int)u) << 16);
}
__device__ __forceinline__ short f_to_bf16bits(float v) {
    bf16 h = __float2bfloat16(v);
    short s; __builtin_memcpy(&s, &h, 2); return s;
}
__device__ __forceinline__ float sigmoidf_(float x) { return 1.0f / (1.0f + expf(-x)); }

// ---------------------------------------------------------------------------
__global__ __launch_bounds__(256) void zero_kernel(float* __restrict__ p, int n) {
    int i = blockIdx.x * 256 + threadIdx.x;
    if (i < n) p[i] = 0.0f;
}

// ---------------------------------------------------------------------------
// pack conv weights fp32 [512][512][KW] -> bf16 [512][512*KWP] (zero-fill t>=KW)
// ---------------------------------------------------------------------------
template <int KWP>
__global__ __launch_bounds__(256) void pack_w(const float* __restrict__ w, short* __restrict__ wpk, int KW) {
    int idx = blockIdx.x * 256 + threadIdx.x;
    const int N = 512 * 512 * KWP;
    if (idx >= N) return;
    int co = idx / (512 * KWP);
    int r = idx - co * (512 * KWP);
    int ci = r / KWP, t = r - ci * KWP;
    float v = (t < KW) ? w[((size_t)co * 512 + ci) * KW + t] : 0.0f;
    wpk[idx] = f_to_bf16bits(v);
}

// ---------------------------------------------------------------------------
// MFMA conv: out[n,co,l] = sum_{ci,t} w[co,ci,t] * in[n,ci,ST*l-pad+t]
// as GEMM M=co(64/block) N=l(64/block) K=512*KWP, bf16 MFMA 16x16x32.
// Block 256 thr = 4 waves; wave w -> co sub-tile w*16, all 64 l.
// ---------------------------------------------------------------------------
template <int KWP, int ST, int SPANP>
__global__ __launch_bounds__(256) void conv_mfma(const bf16* __restrict__ in,     // [nz][512][Lin]
                                                 const short* __restrict__ wpk,   // [512][512*KWP]
                                                 bf16* __restrict__ out,          // [nz][512][Lout]
                                                 int Lin, int Lout, int pad) {
    constexpr int KTOT = 512 * KWP;
    constexpr int NCHUNK = KTOT / 32;
    constexpr int CCC = 32 / KWP;               // channels per 32-K chunk
    constexpr int SPAN_NEED = ST * 63 + KWP;    // staged input span per channel

    const int l0 = blockIdx.x * 64;
    const int co0 = blockIdx.y * 64;
    const int tid = threadIdx.x;
    const int lane = tid & 63;
    const int wv = tid >> 6;
    const int m = lane & 15;
    const int quad = lane >> 4;

    in += (size_t)blockIdx.z * 512 * Lin;
    out += (size_t)blockIdx.z * 512 * Lout;

    __shared__ __align__(16) short As[64][40];       // [co][k] bf16 bits, stride 40 (2-way free)
    __shared__ __align__(16) short rows[CCC][SPANP]; // staged input rows

    const int base = ST * l0 - pad;
    const int arow = tid >> 2, aseg = tid & 3;       // A staging: 16B per thread

    float4v acc[4];
    for (int i = 0; i < 4; ++i) acc[i] = (float4v){0.f, 0.f, 0.f, 0.f};

    for (int kc = 0; kc < NCHUNK; ++kc) {
        const int k0 = kc * 32;
        const int ci0 = kc * CCC;
        __syncthreads();
        // stage A tile: 64 co x 32 k
        {
            const short* src = wpk + (size_t)(co0 + arow) * KTOT + k0 + aseg * 8;
            *(uint4*)&As[arow][aseg * 8] = *(const uint4*)src;
        }
        // stage input rows (coalesced, zero-filled at edges)
        for (int e = tid; e < CCC * SPAN_NEED; e += 256) {
            int cc = e / SPAN_NEED, jj = e - cc * SPAN_NEED;
            int g = base + jj;
            short v = 0;
            if (g >= 0 && g < Lin) v = ((const short*)in)[(size_t)(ci0 + cc) * Lin + g];
            rows[cc][jj] = v;
        }
        __syncthreads();

        // A fragment: A[m=lane&15][k=quad*8+j]
        short8v afrag = *(const short8v*)&As[wv * 16 + m][quad * 8];

#pragma unroll
        for (int nsub = 0; nsub < 4; ++nsub) {
            const int lloc = nsub * 16 + m;
            short8v bfrag;
            if constexpr (KWP == 8) {
                const short* rp = &rows[quad][ST * lloc];
#pragma unroll
                for (int j = 0; j < 8; ++j) bfrag[j] = rp[j];
            } else {  // KWP == 4
                const short* rp0 = &rows[quad * 2 + 0][ST * lloc];
                const short* rp1 = &rows[quad * 2 + 1][ST * lloc];
#pragma unroll
                for (int j = 0; j < 4; ++j) { bfrag[j] = rp0[j]; bfrag[4 + j] = rp1[j]; }
            }
            acc[nsub] = __builtin_amdgcn_mfma_f32_16x16x32_bf16(afrag, bfrag, acc[nsub], 0, 0, 0);
        }
    }

    // epilogue: D[row=quad*4+reg][col=lane&15]
#pragma unroll
    for (int nsub = 0; nsub < 4; ++nsub) {
        const int l = l0 + nsub * 16 + m;
        if (l < Lout) {
#pragma unroll
            for (int reg = 0; reg < 4; ++reg) {
                const int co = co0 + wv * 16 + quad * 4 + reg;
                out[(size_t)co * Lout + l] = __float2bfloat16(acc[nsub][reg]);
            }
        }
    }
}

// ---------------------------------------------------------------------------
// conv1 stats: per-channel sum/sumsq of PRE-BN conv1 output. No y1 store.
// ---------------------------------------------------------------------------
__global__ __launch_bounds__(256) void conv1_stats(const float* __restrict__ x,
                                                   const float* __restrict__ w1,
                                                   float* __restrict__ sums) {
    const int n = blockIdx.x;
    const int tid = threadIdx.x;
    __shared__ __align__(16) float ws[5120];
    __shared__ __align__(16) float xs[5 * 256 + 10];
    for (int e = tid; e < 5120; e += 256) ws[e] = w1[e];
    const int co0 = tid, co1 = tid + 256;
    float a1_0 = 0.0f, a2_0 = 0.0f, a1_1 = 0.0f, a2_1 = 0.0f;
    for (int i = 0; i < 4; ++i) {
        const int c = blockIdx.y * 4 + i;
        const int base = c * 1280 - 3;
        __syncthreads();
        for (int e = tid; e < 1290; e += 256) {
            int g = base + e;
            xs[e] = (g >= 0 && g < 20480) ? x[(size_t)n * 20480 + g] : 0.0f;
        }
        __syncthreads();
        for (int l = 0; l < 256; ++l) {
            float y0 = 0.0f, y1v = 0.0f;
#pragma unroll
            for (int t = 0; t < 10; ++t) {
                float xv = xs[5 * l + t];
                y0 += ws[co0 * 10 + t] * xv;
                y1v += ws[co1 * 10 + t] * xv;
            }
            a1_0 += y0; a2_0 += y0 * y0;
            a1_1 += y1v; a2_1 += y1v * y1v;
        }
    }
    atomicAdd(&sums[co0], a1_0); atomicAdd(&sums[512 + co0], a2_0);
    atomicAdd(&sums[co1], a1_1); atomicAdd(&sums[512 + co1], a2_1);
}

__global__ __launch_bounds__(256) void bn1_finalize(const float* __restrict__ sums,
                                                    const float* __restrict__ gamma,
                                                    const float* __restrict__ beta,
                                                    float* __restrict__ ss) {
    int c = blockIdx.x * 256 + threadIdx.x;
    if (c >= 512) return;
    const float invM = 1.0f / (64.0f * 4096.0f);
    float mean = sums[c] * invM;
    float var = sums[512 + c] * invM - mean * mean;
    float sc = rsqrtf(var + 1e-5f) * gamma[c];
    ss[c] = sc;
    ss[512 + c] = beta[c] - mean * sc;
}

// ---------------------------------------------------------------------------
// conv1 apply (per 8-batch chunk): y1c[nloc,co,l] = relu(sc*conv1 + sh), bf16
// ---------------------------------------------------------------------------
__global__ __launch_bounds__(256) void conv1_apply(const float* __restrict__ x,
                                                   const float* __restrict__ w1,
                                                   const float* __restrict__ ss,
                                                   bf16* __restrict__ y1c, int nbase) {
    __shared__ __align__(16) float xs[5 * 64 + 10 + 1];
    __shared__ __align__(16) float ws[5120];
    const int lt = blockIdx.x, nloc = blockIdx.y;
    const int n = nbase + nloc;
    const int l0 = lt * 64;
    const int base = l0 * 5 - 3;
    for (int e = threadIdx.x; e < 5 * 64 + 10; e += 256) {
        int g = base + e;
        xs[e] = (g >= 0 && g < 20480) ? x[(size_t)n * 20480 + g] : 0.0f;
    }
    for (int e = threadIdx.x; e < 5120; e += 256) ws[e] = w1[e];
    __syncthreads();
    for (int idx = threadIdx.x; idx < 512 * 64; idx += 256) {
        int co = idx >> 6, l = idx & 63;
        float acc = 0.0f;
#pragma unroll
        for (int t = 0; t < 10; ++t) acc += ws[co * 10 + t] * xs[5 * l + t];
        float v = fmaxf(acc * ss[co] + ss[512 + co], 0.0f);
        y1c[((size_t)nloc * 512 + co) * 4096 + l0 + l] = __float2bfloat16(v);
    }
}

// ---------------------------------------------------------------------------
// BN batch-stats + apply (affine + relu), in place
// ---------------------------------------------------------------------------
template <typename T>
__global__ __launch_bounds__(256) void bn_stats(const T* __restrict__ y, float* __restrict__ sums, int L) {
    const int c = blockIdx.x;
    float s1 = 0.0f, s2 = 0.0f;
    for (int n = 0; n < 64; ++n) {
        const T* p = y + ((size_t)n * 512 + c) * L;
        for (int l = blockIdx.y * 256 + threadIdx.x; l < L; l += gridDim.y * 256) {
            float v = ld_f(p, l);
            s1 += v; s2 += v * v;
        }
    }
    __shared__ float r1[256], r2[256];
    r1[threadIdx.x] = s1; r2[threadIdx.x] = s2;
    __syncthreads();
    for (int o = 128; o > 0; o >>= 1) {
        if (threadIdx.x < o) { r1[threadIdx.x] += r1[threadIdx.x + o]; r2[threadIdx.x] += r2[threadIdx.x + o]; }
        __syncthreads();
    }
    if (threadIdx.x == 0) {
        atomicAdd(&sums[c], r1[0]);
        atomicAdd(&sums[512 + c], r2[0]);
    }
}

template <typename T>
__global__ __launch_bounds__(256) void bn_apply(T* __restrict__ y, const float* __restrict__ sums,
                                                const float* __restrict__ gamma, const float* __restrict__ beta,
                                                int layer, int L) {
    const int c = blockIdx.x;
    const float invM = 1.0f / (64.0f * (float)L);
    float mean = sums[c] * invM;
    float var = sums[512 + c] * invM - mean * mean;
    float sc = rsqrtf(var + 1e-5f) * gamma[layer * 512 + c];
    float sh = beta[layer * 512 + c] - mean * sc;
    for (int n = 0; n < 64; ++n) {
        T* p = y + ((size_t)n * 512 + c) * L;
        for (int l = blockIdx.y * 256 + threadIdx.x; l < L; l += gridDim.y * 256) {
            float v = ld_f(p, l);
            st_f(p, l, fmaxf(v * sc + sh, 0.0f));
        }
    }
}

// ---------------------------------------------------------------------------
// x_proj[b,t,g] = sum_d y5[b,d,t]*wih[g,d] + bih[g]   (t <= ts)
// ---------------------------------------------------------------------------
__global__ __launch_bounds__(256) void xproj_kernel(const bf16* __restrict__ y5, const float* __restrict__ wih,
                                                    const float* __restrict__ bih, float* __restrict__ xp,
                                                    const int* __restrict__ tsamp) {
    const int g0 = blockIdx.x * 64, t0 = blockIdx.y * 64;
    const int b = blockIdx.z;
    const int tid = threadIdx.x;
    const int tx = tid & 15, ty = tid >> 4;
    const int ts = tsamp[0];

    __shared__ __align__(16) float As[32][68];
    __shared__ __align__(16) float Bst[32][68];
    float acc[4][4] = {};
    const bf16* ybase = y5 + (size_t)b * 512 * 409;
    for (int d0 = 0; d0 < 512; d0 += 32) {
        __syncthreads();
        for (int e = tid; e < 32 * 64; e += 256) {
            int dj = e >> 6, tl = e & 63;
            As[dj][tl] = ld_f(ybase, (size_t)(d0 + dj) * 409 + t0 + tl);
        }
        for (int e = tid; e < 64 * 32; e += 256) {
            int gr = e >> 5, dj = e & 31;
            Bst[dj][gr] = wih[(size_t)(g0 + gr) * 512 + d0 + dj];
        }
        __syncthreads();
#pragma unroll
        for (int k = 0; k < 32; ++k) {
            float4 a = *(const float4*)&As[k][ty * 4];
            float4 bv = *(const float4*)&Bst[k][tx * 4];
            acc[0][0] += a.x * bv.x; acc[0][1] += a.x * bv.y; acc[0][2] += a.x * bv.z; acc[0][3] += a.x * bv.w;
            acc[1][0] += a.y * bv.x; acc[1][1] += a.y * bv.y; acc[1][2] += a.y * bv.z; acc[1][3] += a.y * bv.w;
            acc[2][0] += a.z * bv.x; acc[2][1] += a.z * bv.y; acc[2][2] += a.z * bv.z; acc[2][3] += a.z * bv.w;
            acc[3][0] += a.w * bv.x; acc[3][1] += a.w * bv.y; acc[3][2] += a.w * bv.z; acc[3][3] += a.w * bv.w;
        }
    }
#pragma unroll
    for (int i = 0; i < 4; ++i) {
        int t = t0 + ty * 4 + i;
        if (t <= ts) {
            float4 o;
            o.x = acc[i][0] + bih[g0 + tx * 4 + 0];
            o.y = acc[i][1] + bih[g0 + tx * 4 + 1];
            o.z = acc[i][2] + bih[g0 + tx * 4 + 2];
            o.w = acc[i][3] + bih[g0 + tx * 4 + 3];
            *(float4*)&xp[((size_t)b * 256 + t) * 768 + g0 + tx * 4] = o;
        }
    }
}

// ---------------------------------------------------------------------------
__global__ __launch_bounds__(256) void pack_whh(const float* __restrict__ whh, ushort4* __restrict__ wpk) {
    int idx = blockIdx.x * 256 + threadIdx.x;
    if (idx >= 64 * 768) return;
    int d4 = idx / 768, g = idx - d4 * 768;
    float4 v = *(const float4*)(whh + (size_t)g * 256 + d4 * 4);
    ushort4 o;
    o.x = (unsigned short)f_to_bf16bits(v.x);
    o.y = (unsigned short)f_to_bf16bits(v.y);
    o.z = (unsigned short)f_to_bf16bits(v.z);
    o.w = (unsigned short)f_to_bf16bits(v.w);
    wpk[idx] = o;
}

// ---------------------------------------------------------------------------
// GRU: one block per batch element, h (256) in LDS, ts+1 sequential steps.
// ---------------------------------------------------------------------------
__global__ __launch_bounds__(256) void gru_kernel(const float* __restrict__ xproj, const ushort4* __restrict__ wpk,
                                                  const float* __restrict__ hidden, const float* __restrict__ bhh,
                                                  float* __restrict__ hlast, const int* __restrict__ tsamp) {
    const int b = blockIdx.x;
    const int g = threadIdx.x;
    __shared__ __align__(16) float h[256];
    h[g] = hidden[(size_t)b * 256 + g];
    const float bhr = bhh[g], bhz = bhh[256 + g], bhn = bhh[512 + g];
    const int ts = tsamp[0];
    const float* xp = xproj + (size_t)b * 256 * 768;
    __syncthreads();
    for (int step = 0; step <= ts; ++step) {
        float ar = 0.0f, az = 0.0f, an = 0.0f;
#pragma unroll 4
        for (int d4 = 0; d4 < 64; ++d4) {
            float4 hv = *(const float4*)&h[d4 * 4];
            ushort4 wr = wpk[d4 * 768 + g];
            ushort4 wz = wpk[d4 * 768 + 256 + g];
            ushort4 wn = wpk[d4 * 768 + 512 + g];
            ar += bf16bits_to_f(wr.x) * hv.x + bf16bits_to_f(wr.y) * hv.y +
                  bf16bits_to_f(wr.z) * hv.z + bf16bits_to_f(wr.w) * hv.w;
            az += bf16bits_to_f(wz.x) * hv.x + bf16bits_to_f(wz.y) * hv.y +
                  bf16bits_to_f(wz.z) * hv.z + bf16bits_to_f(wz.w) * hv.w;
            an += bf16bits_to_f(wn.x) * hv.x + bf16bits_to_f(wn.y) * hv.y +
                  bf16bits_to_f(wn.z) * hv.z + bf16bits_to_f(wn.w) * hv.w;
        }
        float xr = xp[(size_t)step * 768 + g];
        float xz = xp[(size_t)step * 768 + 256 + g];
        float xn = xp[(size_t)step * 768 + 512 + g];
        float r = sigmoidf_(xr + ar + bhr);
        float z = sigmoidf_(xz + az + bhz);
        float nn = tanhf(xn + r * (an + bhn));
        float hnew = (1.0f - z) * nn + z * h[g];
        __syncthreads();
        h[g] = hnew;
        __syncthreads();
    }
    hlast[(size_t)b * 256 + g] = h[g];
}

// ---------------------------------------------------------------------------
__global__ __launch_bounds__(256) void pred_kernel(const float* __restrict__ hlast, const float* __restrict__ wkw,
                                                   const float* __restrict__ wkb, float* __restrict__ pred) {
    const int c = blockIdx.x, t = blockIdx.y;
    __shared__ __align__(16) float hs[256];
    hs[threadIdx.x] = hlast[(size_t)c * 256 + threadIdx.x];
    __syncthreads();
    for (int k = threadIdx.x; k < 512; k += 256) {
        const float* wr = wkw + ((size_t)t * 512 + k) * 256;
        float acc = 0.0f;
        for (int d = 0; d < 256; d += 4) {
            float4 w4 = *(const float4*)&wr[d];
            acc += w4.x * hs[d] + w4.y * hs[d + 1] + w4.z * hs[d + 2] + w4.w * hs[d + 3];
        }
        pred[((size_t)t * 64 + c) * 512 + k] = acc + wkb[(size_t)t * 512 + k];
    }
}

// ---------------------------------------------------------------------------
__global__ __launch_bounds__(64) void total_kernel(const bf16* __restrict__ y5, const float* __restrict__ pred,
                                                   float* __restrict__ total, const int* __restrict__ tsamp) {
    const int b = blockIdx.x, t = blockIdx.y;
    const int col = tsamp[0] + 1 + t;
    __shared__ __align__(16) float es[512];
    for (int k = threadIdx.x; k < 512; k += 64) es[k] = ld_f(y5, ((size_t)b * 512 + k) * 409 + col);
    __syncthreads();
    const int c = threadIdx.x;
    const float* pr = pred + ((size_t)t * 64 + c) * 512;
    float acc = 0.0f;
    for (int k = 0; k < 512; k += 4) {
        float4 p4 = *(const float4*)&pr[k];
        acc += p4.x * es[k] + p4.y * es[k + 1] + p4.z * es[k + 2] + p4.w * es[k + 3];
    }
    total[((size_t)t * 64 + b) * 64 + c] = acc;
}

// ---------------------------------------------------------------------------
__global__ __launch_bounds__(256) void final_kernel(const float* __restrict__ total, const float* __restrict__ hlast,
                                                    float* __restrict__ out) {
    __shared__ float rowM[768], rowS[768];
    __shared__ float red[256];
    __shared__ int cnt[64];
    const int tid = threadIdx.x;
    float local = 0.0f;
    for (int row = tid; row < 768; row += 256) {
        const float* r = total + (size_t)row * 64;
        float m = r[0];
        for (int c = 1; c < 64; ++c) m = fmaxf(m, r[c]);
        float s = 0.0f;
        for (int c = 0; c < 64; ++c) s += expf(r[c] - m);
        rowM[row] = m; rowS[row] = s;
        int bcol = row & 63;
        local += r[bcol] - m - logf(s);
    }
    red[tid] = local;
    __syncthreads();
    for (int o = 128; o > 0; o >>= 1) {
        if (tid < o) red[tid] += red[tid + o];
        __syncthreads();
    }
    if (tid == 0) out[1] = red[0] / (-768.0f);
    if (tid < 64) {
        const int c = tid;
        float best = -1e30f; int bi = -1;
        for (int b = 0; b < 64; ++b) {
            int row = 11 * 64 + b;
            float v = expf(total[(size_t)row * 64 + c] - rowM[row]) / rowS[row];
            if (v > best) { best = v; bi = b; }
        }
        cnt[c] = (bi == c) ? 1 : 0;
    }
    __syncthreads();
    if (tid == 0) {
        int s = 0;
        for (int c = 0; c < 64; ++c) s += cnt[c];
        out[0] = (float)s / 64.0f;
    }
    for (int i = tid; i < 16384; i += 256) out[2 + i] = hlast[i];
}

// ---------------------------------------------------------------------------
extern "C" void kernel_launch(void* const* d_in, const int* in_sizes, int n_in,
                              void* d_out, int out_size, void* d_ws, size_t ws_size,
                              hipStream_t stream) {
    const float *x = nullptr, *hidden = nullptr, *gamma = nullptr, *beta = nullptr;
    const float *wih = nullptr, *whh = nullptr, *bih = nullptr, *bhh = nullptr;
    const float *wkw = nullptr, *wkb = nullptr;
    const float *w1 = nullptr, *w2 = nullptr, *w3 = nullptr, *w4 = nullptr, *w5 = nullptr;
    const int* tsamp = nullptr;
    for (int i = 0; i < n_in; ++i) {
        const float* p = (const float*)d_in[i];
        switch (in_sizes[i]) {
            case 1310720: x = p; break;
            case 16384:   hidden = p; break;
            case 2560:    if (!gamma) gamma = p; else beta = p; break;
            case 393216:  wih = p; break;
            case 196608:  whh = p; break;
            case 768:     if (!bih) bih = p; else bhh = p; break;
            case 1572864: wkw = p; break;
            case 6144:    wkb = p; break;
            case 1:       tsamp = (const int*)d_in[i]; break;
            case 5120:    w1 = p; break;
            case 2097152: w2 = p; break;
            case 1048576: w3 = p; break;
            case 786432:  if (!w4) w4 = p; else w5 = p; break;
            default: break;
        }
    }

    // Workspace layout (peak 91.45 MB — within the 92.25 MB proven in round 2):
    //   slotA [0, 53.674M):    y2 -> y4 -> xp
    //   Wslot [53.676M, 57.87M): per-layer packed bf16 weights (reused), then GRU tail
    //   slotB [57.872M, 91.43M): y1c -> y3 -> y5
    //   sums/ss1 at 91.43M
    char* ws = (char*)d_ws;
    bf16*  y2    = (bf16*)(ws + 0);                 // 53,673,984 B
    bf16*  y4    = (bf16*)(ws + 0);                 // 26,804,224 B (after y2 dead)
    float* xp    = (float*)(ws + 0);                // 50,331,648 B (after y4 dead)
    short* wconv = (short*)(ws + 53676032ull);      //  4,194,304 B (encoder phase)
    bf16*  y1c   = (bf16*)(ws + 57872384ull);       // 33,554,432 B (8-batch chunk)
    bf16*  y3    = (bf16*)(ws + 57872384ull);       // 26,804,224 B (after y1c dead)
    bf16*  y5    = (bf16*)(ws + 57872384ull);       // 26,804,224 B (after y3 dead)
    float* sums  = (float*)(ws + 91426816ull);      //     20,480 B
    float* ss1   = (float*)(ws + 91447296ull);      //      4,096 B -> end 91,451,392
    // GRU-phase tail overlapping Wslot (dead after encoder):
    ushort4* wpk = (ushort4*)(ws + 53676032ull);    //    393,216 B
    float* hlast = (float*)(ws + 54069248ull);      //     65,536 B
    float* pred  = (float*)(ws + 54134784ull);      //  1,572,864 B
    float* totl  = (float*)(ws + 55707648ull);      //    196,608 B -> end 55,904,256

    // --- layer 1 stats (no y1 materialization) ---
    zero_kernel<<<20, 256, 0, stream>>>(sums, 5120);
    conv1_stats<<<dim3(64, 4), 256, 0, stream>>>(x, w1, sums);
    bn1_finalize<<<2, 256, 0, stream>>>(sums, gamma, beta, ss1);

    // --- layer 2: pack w2, then conv1-apply + MFMA conv per 8-batch chunk ---
    pack_w<8><<<8192, 256, 0, stream>>>(w2, wconv, 8);
    for (int nb = 0; nb < 64; nb += 8) {
        conv1_apply<<<dim3(64, 8), 256, 0, stream>>>(x, w1, ss1, y1c, nb);
        conv_mfma<8, 5, 336><<<dim3(13, 8, 8), 256, 0, stream>>>(
            y1c, wconv, y2 + (size_t)nb * 512 * 819, 4096, 819, 2);
    }
    bn_stats<bf16><<<dim3(512, 3), 256, 0, stream>>>(y2, sums + 1024, 819);
    bn_apply<bf16><<<dim3(512, 3), 256, 0, stream>>>(y2, sums + 1024, gamma, beta, 1, 819);

    // --- layer 3 ---
    pack_w<4><<<4096, 256, 0, stream>>>(w3, wconv, 4);
    conv_mfma<4, 2, 144><<<dim3(7, 8, 64), 256, 0, stream>>>(y2, wconv, y3, 819, 409, 1);
    bn_stats<bf16><<<dim3(512, 2), 256, 0, stream>>>(y3, sums + 2048, 409);
    bn_apply<bf16><<<dim3(512, 2), 256, 0, stream>>>(y3, sums + 2048, gamma, beta, 2, 409);

    // --- layer 4 (KW=3 zero-padded to 4) ---
    pack_w<4><<<4096, 256, 0, stream>>>(w4, wconv, 3);
    conv_mfma<4, 1, 80><<<dim3(7, 8, 64), 256, 0, stream>>>(y3, wconv, y4, 409, 409, 1);
    bn_stats<bf16><<<dim3(512, 2), 256, 0, stream>>>(y4, sums + 3072, 409);
    bn_apply<bf16><<<dim3(512, 2), 256, 0, stream>>>(y4, sums + 3072, gamma, beta, 3, 409);

    // --- layer 5 (KW=3 zero-padded to 4) ---
    pack_w<4><<<4096, 256, 0, stream>>>(w5, wconv, 3);
    conv_mfma<4, 1, 80><<<dim3(7, 8, 64), 256, 0, stream>>>(y4, wconv, y5, 409, 409, 1);
    bn_stats<bf16><<<dim3(512, 2), 256, 0, stream>>>(y5, sums + 4096, 409);
    bn_apply<bf16><<<dim3(512, 2), 256, 0, stream>>>(y5, sums + 4096, gamma, beta, 4, 409);

    // --- GRU ---
    pack_whh<<<192, 256, 0, stream>>>(whh, wpk);
    xproj_kernel<<<dim3(12, 4, 64), 256, 0, stream>>>(y5, wih, bih, xp, tsamp);
    gru_kernel<<<64, 256, 0, stream>>>(xp, wpk, hidden, bhh, hlast, tsamp);

    // --- contrastive head ---
    pred_kernel<<<dim3(64, 12), 256, 0, stream>>>(hlast, wkw, wkb, pred);
    total_kernel<<<dim3(64, 12), 64, 0, stream>>>(y5, pred, totl, tsamp);
    final_kernel<<<1, 256, 0, stream>>>(totl, hlast, (float*)d_out);
}

// Round 4
// 5350.692 us; speedup vs baseline: 1.9934x; 1.3313x over previous
//
#include <hip/hip_runtime.h>
#include <hip/hip_bf16.h>

typedef __hip_bfloat16 bf16;
typedef short short8v __attribute__((ext_vector_type(8)));
typedef float float4v __attribute__((ext_vector_type(4)));

__device__ __forceinline__ float ld_f(const float* p, size_t i) { return p[i]; }
__device__ __forceinline__ float ld_f(const bf16* p, size_t i) { return __bfloat162float(p[i]); }
__device__ __forceinline__ void st_f(float* p, size_t i, float v) { p[i] = v; }
__device__ __forceinline__ void st_f(bf16* p, size_t i, float v) { p[i] = __float2bfloat16(v); }
__device__ __forceinline__ short f_to_bf16bits(float v) {
    bf16 h = __float2bfloat16(v);
    short s; __builtin_memcpy(&s, &h, 2); return s;
}
__device__ __forceinline__ float pk_lo(unsigned int u) { return __uint_as_float(u << 16); }
__device__ __forceinline__ float pk_hi(unsigned int u) { return __uint_as_float(u & 0xffff0000u); }
__device__ __forceinline__ float sigmoidf_(float x) { return 1.0f / (1.0f + expf(-x)); }

// ---------------------------------------------------------------------------
__global__ __launch_bounds__(256) void zero_kernel(float* __restrict__ p, int n) {
    int i = blockIdx.x * 256 + threadIdx.x;
    if (i < n) p[i] = 0.0f;
}

// ---------------------------------------------------------------------------
// generic GEMM weight pack: fp32 [M][CIN][KW] -> bf16 [M][CIN*KWP], zero t>=KW
// ---------------------------------------------------------------------------
__global__ __launch_bounds__(256) void pack_gemm(const float* __restrict__ w, short* __restrict__ out,
                                                 int M, int CIN, int KW, int KWP) {
    int idx = blockIdx.x * 256 + threadIdx.x;
    int tot = M * CIN * KWP;
    if (idx >= tot) return;
    int co = idx / (CIN * KWP);
    int r = idx - co * (CIN * KWP);
    int ci = r / KWP, t = r - ci * KWP;
    float v = (t < KW) ? w[((size_t)co * CIN + ci) * KW + t] : 0.0f;
    out[idx] = f_to_bf16bits(v);
}

// ---------------------------------------------------------------------------
// GRU weight pack: whh fp32 (768,256) -> uint wp2[(kq*256+g)*96 + gate*32 + pr]
// pair = bf16(whh[gate*256+g][kq*64+2*pr]) | bf16(...[+1]) << 16
// ---------------------------------------------------------------------------
__global__ __launch_bounds__(256) void pack_whh2(const float* __restrict__ whh, unsigned int* __restrict__ wp2) {
    int idx = blockIdx.x * 256 + threadIdx.x;
    if (idx >= 98304) return;
    int q = idx / 96;
    int rem = idx - q * 96;
    int kq = q >> 8, g = q & 255;
    int gate = rem >> 5, pr = rem & 31;
    int row = gate * 256 + g;
    int d = kq * 64 + pr * 2;
    unsigned int lo = (unsigned short)f_to_bf16bits(whh[(size_t)row * 256 + d]);
    unsigned int hi = (unsigned short)f_to_bf16bits(whh[(size_t)row * 256 + d + 1]);
    wp2[idx] = lo | (hi << 16);
}

// ---------------------------------------------------------------------------
// MFMA conv: out[n,co,l] = sum_{ci,t} w[co,ci,t]*in[n,ci,ST*l-pad+t]
// Block 256 thr (4 waves): tile 128co x 64l. Wave wv: l-range wv*16..+16, all 128 co.
// Per 32-K chunk per wave: 1 B-gather (8 scalar), 8 A ds_read_b128, 8 MFMAs.
// ---------------------------------------------------------------------------
template <int KWP, int ST, int SPANP>
__global__ __launch_bounds__(256) void conv_mfma(const bf16* __restrict__ in,
                                                 const short* __restrict__ wpk,
                                                 bf16* __restrict__ out,
                                                 int Lin, int Lout, int pad) {
    constexpr int KTOT = 512 * KWP;
    constexpr int NCHUNK = KTOT / 32;
    constexpr int CCC = 32 / KWP;
    constexpr int SPAN_NEED = ST * 63 + KWP;

    const int l0 = blockIdx.x * 64;
    const int co0 = blockIdx.y * 128;
    const int tid = threadIdx.x;
    const int lane = tid & 63;
    const int wv = tid >> 6;
    const int m = lane & 15;
    const int quad = lane >> 4;

    in += (size_t)blockIdx.z * 512 * Lin;
    out += (size_t)blockIdx.z * 512 * Lout;

    __shared__ __align__(16) short As[128][40];      // [co][k], 80B stride (16B-mult)
    __shared__ __align__(16) short rows[CCC][SPANP];

    const int base = ST * l0 - pad;
    const int lloc = wv * 16 + m;

    float4v acc[8];
#pragma unroll
    for (int i = 0; i < 8; ++i) acc[i] = (float4v){0.f, 0.f, 0.f, 0.f};

    for (int kc = 0; kc < NCHUNK; ++kc) {
        const int k0 = kc * 32;
        const int ci0 = kc * CCC;
        __syncthreads();
        // stage A: 128 x 32 shorts, 2 x 16B per thread
#pragma unroll
        for (int r = 0; r < 2; ++r) {
            int e = tid + r * 256;
            int row = e >> 2, seg = e & 3;
            *(uint4*)&As[row][seg * 8] =
                *(const uint4*)(wpk + (size_t)(co0 + row) * KTOT + k0 + seg * 8);
        }
        // stage input rows
        for (int e = tid; e < CCC * SPAN_NEED; e += 256) {
            int cc = e / SPAN_NEED, jj = e - cc * SPAN_NEED;
            int g = base + jj;
            short v = 0;
            if (g >= 0 && g < Lin) v = ((const short*)in)[(size_t)(ci0 + cc) * Lin + g];
            rows[cc][jj] = v;
        }
        __syncthreads();

        // B fragment for this wave-lane: B[n=lane&15 -> l][k=quad*8+j]
        short8v bfrag;
        if constexpr (KWP == 8) {
            const short* rp = &rows[quad][ST * lloc];
#pragma unroll
            for (int j = 0; j < 8; ++j) bfrag[j] = rp[j];
        } else {  // KWP == 4
            const short* rp0 = &rows[quad * 2 + 0][ST * lloc];
            const short* rp1 = &rows[quad * 2 + 1][ST * lloc];
#pragma unroll
            for (int j = 0; j < 4; ++j) { bfrag[j] = rp0[j]; bfrag[4 + j] = rp1[j]; }
        }
#pragma unroll
        for (int s = 0; s < 8; ++s) {
            short8v afrag = *(const short8v*)&As[s * 16 + m][quad * 8];
            acc[s] = __builtin_amdgcn_mfma_f32_16x16x32_bf16(afrag, bfrag, acc[s], 0, 0, 0);
        }
    }

    const int l = l0 + lloc;
    if (l < Lout) {
#pragma unroll
        for (int s = 0; s < 8; ++s) {
#pragma unroll
            for (int reg = 0; reg < 4; ++reg) {
                const int co = co0 + s * 16 + quad * 4 + reg;
                out[(size_t)co * Lout + l] = __float2bfloat16(acc[s][reg]);
            }
        }
    }
}

// ---------------------------------------------------------------------------
// conv1 via MFMA: K=32 (taps 0..9 real, rest zero). Block: 128co x 64l.
// A fragments loaded directly from global (L2-resident 32KB w1p).
// Epilogue fuses BN scale/shift + relu.
// ---------------------------------------------------------------------------
__global__ __launch_bounds__(256) void conv1_mfma(const float* __restrict__ x,
                                                  const short* __restrict__ w1p,
                                                  const float* __restrict__ ss,
                                                  bf16* __restrict__ y1c, int nbase) {
    const int l0 = blockIdx.x * 64;
    const int co0 = blockIdx.y * 128;
    const int nloc = blockIdx.z;
    const int n = nbase + nloc;
    const int tid = threadIdx.x;
    const int lane = tid & 63;
    const int wv = tid >> 6;
    const int m = lane & 15;
    const int quad = lane >> 4;

    __shared__ __align__(16) short xs[352];    // span 5*63+32 = 347
    const int base = 5 * l0 - 3;
    for (int e = tid; e < 347; e += 256) {
        int g = base + e;
        float v = (g >= 0 && g < 20480) ? x[(size_t)n * 20480 + g] : 0.0f;
        xs[e] = f_to_bf16bits(v);
    }
    __syncthreads();

    const int lloc = wv * 16 + m;
    short8v bfrag;
    {
        const short* rp = &xs[5 * lloc + quad * 8];
#pragma unroll
        for (int j = 0; j < 8; ++j) bfrag[j] = rp[j];
    }
    float4v acc[8];
#pragma unroll
    for (int s = 0; s < 8; ++s) {
        short8v afrag = *(const short8v*)(w1p + (size_t)(co0 + s * 16 + m) * 32 + quad * 8);
        float4v z = (float4v){0.f, 0.f, 0.f, 0.f};
        acc[s] = __builtin_amdgcn_mfma_f32_16x16x32_bf16(afrag, bfrag, z, 0, 0, 0);
    }
    const int l = l0 + lloc;
#pragma unroll
    for (int s = 0; s < 8; ++s) {
#pragma unroll
        for (int reg = 0; reg < 4; ++reg) {
            const int co = co0 + s * 16 + quad * 4 + reg;
            float v = fmaxf(acc[s][reg] * ss[co] + ss[512 + co], 0.0f);
            y1c[((size_t)nloc * 512 + co) * 4096 + l] = __float2bfloat16(v);
        }
    }
}

// ---------------------------------------------------------------------------
// conv1 stats: per-channel sum/sumsq of PRE-BN conv1 output (fp32 path).
// ---------------------------------------------------------------------------
__global__ __launch_bounds__(256) void conv1_stats(const float* __restrict__ x,
                                                   const float* __restrict__ w1,
                                                   float* __restrict__ sums) {
    const int n = blockIdx.x;
    const int tid = threadIdx.x;
    __shared__ __align__(16) float ws[5120];
    __shared__ __align__(16) float xs[5 * 256 + 10];
    for (int e = tid; e < 5120; e += 256) ws[e] = w1[e];
    const int co0 = tid, co1 = tid + 256;
    float a1_0 = 0.0f, a2_0 = 0.0f, a1_1 = 0.0f, a2_1 = 0.0f;
    for (int i = 0; i < 4; ++i) {
        const int c = blockIdx.y * 4 + i;
        const int base = c * 1280 - 3;
        __syncthreads();
        for (int e = tid; e < 1290; e += 256) {
            int g = base + e;
            xs[e] = (g >= 0 && g < 20480) ? x[(size_t)n * 20480 + g] : 0.0f;
        }
        __syncthreads();
        for (int l = 0; l < 256; ++l) {
            float y0 = 0.0f, y1v = 0.0f;
#pragma unroll
            for (int t = 0; t < 10; ++t) {
                float xv = xs[5 * l + t];
                y0 += ws[co0 * 10 + t] * xv;
                y1v += ws[co1 * 10 + t] * xv;
            }
            a1_0 += y0; a2_0 += y0 * y0;
            a1_1 += y1v; a2_1 += y1v * y1v;
        }
    }
    atomicAdd(&sums[co0], a1_0); atomicAdd(&sums[512 + co0], a2_0);
    atomicAdd(&sums[co1], a1_1); atomicAdd(&sums[512 + co1], a2_1);
}

__global__ __launch_bounds__(256) void bn1_finalize(const float* __restrict__ sums,
                                                    const float* __restrict__ gamma,
                                                    const float* __restrict__ beta,
                                                    float* __restrict__ ss) {
    int c = blockIdx.x * 256 + threadIdx.x;
    if (c >= 512) return;
    const float invM = 1.0f / (64.0f * 4096.0f);
    float mean = sums[c] * invM;
    float var = sums[512 + c] * invM - mean * mean;
    float sc = rsqrtf(var + 1e-5f) * gamma[c];
    ss[c] = sc;
    ss[512 + c] = beta[c] - mean * sc;
}

// ---------------------------------------------------------------------------
// BN batch-stats + apply (affine + relu), in place
// ---------------------------------------------------------------------------
template <typename T>
__global__ __launch_bounds__(256) void bn_stats(const T* __restrict__ y, float* __restrict__ sums, int L) {
    const int c = blockIdx.x;
    float s1 = 0.0f, s2 = 0.0f;
    for (int n = 0; n < 64; ++n) {
        const T* p = y + ((size_t)n * 512 + c) * L;
        for (int l = blockIdx.y * 256 + threadIdx.x; l < L; l += gridDim.y * 256) {
            float v = ld_f(p, l);
            s1 += v; s2 += v * v;
        }
    }
    __shared__ float r1[256], r2[256];
    r1[threadIdx.x] = s1; r2[threadIdx.x] = s2;
    __syncthreads();
    for (int o = 128; o > 0; o >>= 1) {
        if (threadIdx.x < o) { r1[threadIdx.x] += r1[threadIdx.x + o]; r2[threadIdx.x] += r2[threadIdx.x + o]; }
        __syncthreads();
    }
    if (threadIdx.x == 0) {
        atomicAdd(&sums[c], r1[0]);
        atomicAdd(&sums[512 + c], r2[0]);
    }
}

template <typename T>
__global__ __launch_bounds__(256) void bn_apply(T* __restrict__ y, const float* __restrict__ sums,
                                                const float* __restrict__ gamma, const float* __restrict__ beta,
                                                int layer, int L) {
    const int c = blockIdx.x;
    const float invM = 1.0f / (64.0f * (float)L);
    float mean = sums[c] * invM;
    float var = sums[512 + c] * invM - mean * mean;
    float sc = rsqrtf(var + 1e-5f) * gamma[layer * 512 + c];
    float sh = beta[layer * 512 + c] - mean * sc;
    for (int n = 0; n < 64; ++n) {
        T* p = y + ((size_t)n * 512 + c) * L;
        for (int l = blockIdx.y * 256 + threadIdx.x; l < L; l += gridDim.y * 256) {
            float v = ld_f(p, l);
            st_f(p, l, fmaxf(v * sc + sh, 0.0f));
        }
    }
}

// ---------------------------------------------------------------------------
// xproj via MFMA: xp[b,t,g] = sum_d y5[b,d,t]*wih[g,d] + bih[g]
// Block 128g x 64t, K=512 in 16 chunks.
// ---------------------------------------------------------------------------
__global__ __launch_bounds__(256) void xproj_mfma(const bf16* __restrict__ y5,
                                                  const short* __restrict__ wihp,
                                                  const float* __restrict__ bih,
                                                  float* __restrict__ xp,
                                                  const int* __restrict__ tsamp) {
    const int t0 = blockIdx.x * 64;
    const int g0 = blockIdx.y * 128;
    const int b = blockIdx.z;
    const int tid = threadIdx.x;
    const int lane = tid & 63;
    const int wv = tid >> 6;
    const int m = lane & 15;
    const int quad = lane >> 4;
    const int ts = tsamp[0];

    __shared__ __align__(16) short As[128][40];
    __shared__ __align__(16) short Bt[32][66];

    float4v acc[8];
#pragma unroll
    for (int i = 0; i < 8; ++i) acc[i] = (float4v){0.f, 0.f, 0.f, 0.f};

    const short* y5s = (const short*)y5;
    for (int kc = 0; kc < 16; ++kc) {
        const int k0 = kc * 32;
        __syncthreads();
#pragma unroll
        for (int r = 0; r < 2; ++r) {
            int e = tid + r * 256;
            int row = e >> 2, seg = e & 3;
            *(uint4*)&As[row][seg * 8] =
                *(const uint4*)(wihp + (size_t)(g0 + row) * 512 + k0 + seg * 8);
        }
        for (int e = tid; e < 2048; e += 256) {
            int cc = e >> 6, tl = e & 63;
            Bt[cc][tl] = y5s[((size_t)b * 512 + k0 + cc) * 409 + t0 + tl];  // t0+63 <= 255 < 409
        }
        __syncthreads();
        short8v bfrag;
#pragma unroll
        for (int j = 0; j < 8; ++j) bfrag[j] = Bt[quad * 8 + j][wv * 16 + m];
#pragma unroll
        for (int s = 0; s < 8; ++s) {
            short8v afrag = *(const short8v*)&As[s * 16 + m][quad * 8];
            acc[s] = __builtin_amdgcn_mfma_f32_16x16x32_bf16(afrag, bfrag, acc[s], 0, 0, 0);
        }
    }
    const int t = t0 + wv * 16 + m;
    if (t <= ts) {
#pragma unroll
        for (int s = 0; s < 8; ++s) {
#pragma unroll
            for (int reg = 0; reg < 4; ++reg) {
                const int g = g0 + s * 16 + quad * 4 + reg;
                xp[((size_t)b * 256 + t) * 768 + g] = acc[s][reg] + bih[g];
            }
        }
    }
}

// ---------------------------------------------------------------------------
// GRU: 64 blocks x 1024 threads. Thread (g=tid&255, kq=tid>>8) holds whh
// weights for 3 gates x 64 dims as 96 packed-bf16-pair VGPRs. h in LDS fp32.
// ---------------------------------------------------------------------------
__global__ __launch_bounds__(1024) void gru_kernel(const float* __restrict__ xproj,
                                                   const unsigned int* __restrict__ wp2,
                                                   const float* __restrict__ hidden,
                                                   const float* __restrict__ bhh,
                                                   float* __restrict__ hlast,
                                                   const int* __restrict__ tsamp) {
    const int b = blockIdx.x;
    const int tid = threadIdx.x;
    const int g = tid & 255, kq = tid >> 8;
    __shared__ __align__(16) float h[256];
    __shared__ float red[12 * 256];
    if (kq == 0) h[g] = hidden[(size_t)b * 256 + g];

    unsigned int wreg[96];
    {
        const uint4* srcw = (const uint4*)(wp2 + (size_t)(kq * 256 + g) * 96);
#pragma unroll
        for (int i = 0; i < 24; ++i) *(uint4*)&wreg[i * 4] = srcw[i];
    }
    const float bhr = bhh[g], bhz = bhh[256 + g], bhn = bhh[512 + g];
    const int ts = tsamp[0];
    const float* xb = xproj + (size_t)b * 256 * 768;
    __syncthreads();

    for (int step = 0; step <= ts; ++step) {
        float xr = 0.f, xz = 0.f, xn = 0.f;
        if (kq == 0) {
            xr = xb[(size_t)step * 768 + g];
            xz = xb[(size_t)step * 768 + 256 + g];
            xn = xb[(size_t)step * 768 + 512 + g];
        }
        float ar = 0.f, az = 0.f, an = 0.f;
#pragma unroll
        for (int p = 0; p < 16; ++p) {
            float4 hv = *(const float4*)&h[kq * 64 + p * 4];
            unsigned int u;
            u = wreg[p * 2];          ar += pk_lo(u) * hv.x + pk_hi(u) * hv.y;
            u = wreg[p * 2 + 1];      ar += pk_lo(u) * hv.z + pk_hi(u) * hv.w;
            u = wreg[32 + p * 2];     az += pk_lo(u) * hv.x + pk_hi(u) * hv.y;
            u = wreg[32 + p * 2 + 1]; az += pk_lo(u) * hv.z + pk_hi(u) * hv.w;
            u = wreg[64 + p * 2];     an += pk_lo(u) * hv.x + pk_hi(u) * hv.y;
            u = wreg[64 + p * 2 + 1]; an += pk_lo(u) * hv.z + pk_hi(u) * hv.w;
        }
        red[(0 * 4 + kq) * 256 + g] = ar;
        red[(1 * 4 + kq) * 256 + g] = az;
        red[(2 * 4 + kq) * 256 + g] = an;
        __syncthreads();
        if (kq == 0) {
            float R = xr + bhr + red[0 * 256 + g] + red[1 * 256 + g] + red[2 * 256 + g] + red[3 * 256 + g];
            float Z = xz + bhz + red[4 * 256 + g] + red[5 * 256 + g] + red[6 * 256 + g] + red[7 * 256 + g];
            float N = bhn + red[8 * 256 + g] + red[9 * 256 + g] + red[10 * 256 + g] + red[11 * 256 + g];
            float r = sigmoidf_(R);
            float z = sigmoidf_(Z);
            float nn = tanhf(xn + r * N);
            h[g] = (1.0f - z) * nn + z * h[g];
        }
        __syncthreads();
    }
    if (kq == 0) hlast[(size_t)b * 256 + g] = h[g];
}

// ---------------------------------------------------------------------------
__global__ __launch_bounds__(256) void pred_kernel(const float* __restrict__ hlast, const float* __restrict__ wkw,
                                                   const float* __restrict__ wkb, float* __restrict__ pred) {
    const int c = blockIdx.x, t = blockIdx.y;
    __shared__ __align__(16) float hs[256];
    hs[threadIdx.x] = hlast[(size_t)c * 256 + threadIdx.x];
    __syncthreads();
    for (int k = threadIdx.x; k < 512; k += 256) {
        const float* wr = wkw + ((size_t)t * 512 + k) * 256;
        float acc = 0.0f;
        for (int d = 0; d < 256; d += 4) {
            float4 w4 = *(const float4*)&wr[d];
            acc += w4.x * hs[d] + w4.y * hs[d + 1] + w4.z * hs[d + 2] + w4.w * hs[d + 3];
        }
        pred[((size_t)t * 64 + c) * 512 + k] = acc + wkb[(size_t)t * 512 + k];
    }
}

// ---------------------------------------------------------------------------
__global__ __launch_bounds__(64) void total_kernel(const bf16* __restrict__ y5, const float* __restrict__ pred,
                                                   float* __restrict__ total, const int* __restrict__ tsamp) {
    const int b = blockIdx.x, t = blockIdx.y;
    const int col = tsamp[0] + 1 + t;
    __shared__ __align__(16) float es[512];
    for (int k = threadIdx.x; k < 512; k += 64) es[k] = ld_f(y5, ((size_t)b * 512 + k) * 409 + col);
    __syncthreads();
    const int c = threadIdx.x;
    const float* pr = pred + ((size_t)t * 64 + c) * 512;
    float acc = 0.0f;
    for (int k = 0; k < 512; k += 4) {
        float4 p4 = *(const float4*)&pr[k];
        acc += p4.x * es[k] + p4.y * es[k + 1] + p4.z * es[k + 2] + p4.w * es[k + 3];
    }
    total[((size_t)t * 64 + b) * 64 + c] = acc;
}

// ---------------------------------------------------------------------------
__global__ __launch_bounds__(256) void final_kernel(const float* __restrict__ total, const float* __restrict__ hlast,
                                                    float* __restrict__ out) {
    __shared__ float rowM[768], rowS[768];
    __shared__ float red[256];
    __shared__ int cnt[64];
    const int tid = threadIdx.x;
    float local = 0.0f;
    for (int row = tid; row < 768; row += 256) {
        const float* r = total + (size_t)row * 64;
        float m = r[0];
        for (int c = 1; c < 64; ++c) m = fmaxf(m, r[c]);
        float s = 0.0f;
        for (int c = 0; c < 64; ++c) s += expf(r[c] - m);
        rowM[row] = m; rowS[row] = s;
        int bcol = row & 63;
        local += r[bcol] - m - logf(s);
    }
    red[tid] = local;
    __syncthreads();
    for (int o = 128; o > 0; o >>= 1) {
        if (tid < o) red[tid] += red[tid + o];
        __syncthreads();
    }
    if (tid == 0) out[1] = red[0] / (-768.0f);
    if (tid < 64) {
        const int c = tid;
        float best = -1e30f; int bi = -1;
        for (int b = 0; b < 64; ++b) {
            int row = 11 * 64 + b;
            float v = expf(total[(size_t)row * 64 + c] - rowM[row]) / rowS[row];
            if (v > best) { best = v; bi = b; }
        }
        cnt[c] = (bi == c) ? 1 : 0;
    }
    __syncthreads();
    if (tid == 0) {
        int s = 0;
        for (int c = 0; c < 64; ++c) s += cnt[c];
        out[0] = (float)s / 64.0f;
    }
    for (int i = tid; i < 16384; i += 256) out[2 + i] = hlast[i];
}

// ---------------------------------------------------------------------------
extern "C" void kernel_launch(void* const* d_in, const int* in_sizes, int n_in,
                              void* d_out, int out_size, void* d_ws, size_t ws_size,
                              hipStream_t stream) {
    const float *x = nullptr, *hidden = nullptr, *gamma = nullptr, *beta = nullptr;
    const float *wih = nullptr, *whh = nullptr, *bih = nullptr, *bhh = nullptr;
    const float *wkw = nullptr, *wkb = nullptr;
    const float *w1 = nullptr, *w2 = nullptr, *w3 = nullptr, *w4 = nullptr, *w5 = nullptr;
    const int* tsamp = nullptr;
    for (int i = 0; i < n_in; ++i) {
        const float* p = (const float*)d_in[i];
        switch (in_sizes[i]) {
            case 1310720: x = p; break;
            case 16384:   hidden = p; break;
            case 2560:    if (!gamma) gamma = p; else beta = p; break;
            case 393216:  wih = p; break;
            case 196608:  whh = p; break;
            case 768:     if (!bih) bih = p; else bhh = p; break;
            case 1572864: wkw = p; break;
            case 6144:    wkb = p; break;
            case 1:       tsamp = (const int*)d_in[i]; break;
            case 5120:    w1 = p; break;
            case 2097152: w2 = p; break;
            case 1048576: w3 = p; break;
            case 786432:  if (!w4) w4 = p; else w5 = p; break;
            default: break;
        }
    }

    // Workspace layout (peak 91.48 MB; 92.25 MB proven safe in round 2):
    //   slotA [0, 53.674M):       y2 -> y4 -> xp
    //   Wslot [53.676M, 57.87M):  wconv (encoder) -> wihp/wp2/hlast/pred/totl (GRU+head)
    //   slotB [57.872M, 91.427M): y1c -> y3 -> y5
    //   [91.427M, 91.484M):       sums, ss1, w1p
    char* ws = (char*)d_ws;
    bf16*  y2    = (bf16*)(ws + 0);                      // 53,673,984 B
    bf16*  y4    = (bf16*)(ws + 0);                      // 26,804,224 B
    float* xp    = (float*)(ws + 0);                     // 50,331,648 B
    short* wconv = (short*)(ws + 53676032ull);           //  4,194,304 B (encoder)
    bf16*  y1c   = (bf16*)(ws + 57872384ull);            // 33,554,432 B
    bf16*  y3    = (bf16*)(ws + 57872384ull);            // 26,804,224 B
    bf16*  y5    = (bf16*)(ws + 57872384ull);            // 26,804,224 B
    float* sums  = (float*)(ws + 91426816ull);           //     20,480 B
    float* ss1   = (float*)(ws + 91447296ull);           //      4,096 B
    short* w1p   = (short*)(ws + 91451392ull);           //     32,768 B -> 91,484,160
    // GRU/head tail overlaying Wslot (wconv dead after encoder):
    short* wihp        = (short*)(ws + 53676032ull);     //    786,432 B
    unsigned int* wp2  = (unsigned int*)(ws + 54462464ull); // 393,216 B
    float* hlast = (float*)(ws + 54855680ull);           //     65,536 B
    float* pred  = (float*)(ws + 54921216ull);           //  1,572,864 B
    float* totl  = (float*)(ws + 56494080ull);           //    196,608 B -> 56,690,688

    // --- layer 1 stats ---
    zero_kernel<<<20, 256, 0, stream>>>(sums, 5120);
    conv1_stats<<<dim3(64, 4), 256, 0, stream>>>(x, w1, sums);
    bn1_finalize<<<2, 256, 0, stream>>>(sums, gamma, beta, ss1);
    pack_gemm<<<64, 256, 0, stream>>>(w1, w1p, 512, 1, 10, 32);

    // --- layer 2 (per 8-batch chunk) ---
    pack_gemm<<<8192, 256, 0, stream>>>(w2, wconv, 512, 512, 8, 8);
    for (int nb = 0; nb < 64; nb += 8) {
        conv1_mfma<<<dim3(64, 4, 8), 256, 0, stream>>>(x, w1p, ss1, y1c, nb);
        conv_mfma<8, 5, 324><<<dim3(13, 4, 8), 256, 0, stream>>>(
            y1c, wconv, y2 + (size_t)nb * 512 * 819, 4096, 819, 2);
    }
    bn_stats<bf16><<<dim3(512, 3), 256, 0, stream>>>(y2, sums + 1024, 819);
    bn_apply<bf16><<<dim3(512, 3), 256, 0, stream>>>(y2, sums + 1024, gamma, beta, 1, 819);

    // --- layer 3 ---
    pack_gemm<<<4096, 256, 0, stream>>>(w3, wconv, 512, 512, 4, 4);
    conv_mfma<4, 2, 132><<<dim3(7, 4, 64), 256, 0, stream>>>(y2, wconv, y3, 819, 409, 1);
    bn_stats<bf16><<<dim3(512, 2), 256, 0, stream>>>(y3, sums + 2048, 409);
    bn_apply<bf16><<<dim3(512, 2), 256, 0, stream>>>(y3, sums + 2048, gamma, beta, 2, 409);

    // --- layer 4 ---
    pack_gemm<<<4096, 256, 0, stream>>>(w4, wconv, 512, 512, 3, 4);
    conv_mfma<4, 1, 68><<<dim3(7, 4, 64), 256, 0, stream>>>(y3, wconv, y4, 409, 409, 1);
    bn_stats<bf16><<<dim3(512, 2), 256, 0, stream>>>(y4, sums + 3072, 409);
    bn_apply<bf16><<<dim3(512, 2), 256, 0, stream>>>(y4, sums + 3072, gamma, beta, 3, 409);

    // --- layer 5 ---
    pack_gemm<<<4096, 256, 0, stream>>>(w5, wconv, 512, 512, 3, 4);
    conv_mfma<4, 1, 68><<<dim3(7, 4, 64), 256, 0, stream>>>(y4, wconv, y5, 409, 409, 1);
    bn_stats<bf16><<<dim3(512, 2), 256, 0, stream>>>(y5, sums + 4096, 409);
    bn_apply<bf16><<<dim3(512, 2), 256, 0, stream>>>(y5, sums + 4096, gamma, beta, 4, 409);

    // --- GRU ---
    pack_gemm<<<1536, 256, 0, stream>>>(wih, wihp, 768, 512, 1, 1);
    pack_whh2<<<384, 256, 0, stream>>>(whh, wp2);
    xproj_mfma<<<dim3(4, 6, 64), 256, 0, stream>>>(y5, wihp, bih, xp, tsamp);
    gru_kernel<<<64, 1024, 0, stream>>>(xp, wp2, hidden, bhh, hlast, tsamp);

    // --- contrastive head ---
    pred_kernel<<<dim3(64, 12), 256, 0, stream>>>(hlast, wkw, wkb, pred);
    total_kernel<<<dim3(64, 12), 64, 0, stream>>>(y5, pred, totl, tsamp);
    final_kernel<<<1, 256, 0, stream>>>(totl, hlast, (float*)d_out);
}